// Round 1
// baseline (542.167 us; speedup 1.0000x reference)
//
#include <hip/hip_runtime.h>
#include <math.h>
#include <stdint.h>

// AttnEmo: B=8, S=T=2048, E=512. All-MFMA, fixed-shift unnormalized softmax.
// R8 (on R7):
//  - mask bit-packed once (ballot, fused into split_pair tail blocks):
//    134MB int32 -> 4.2MB bits; logits epilogue does 16 broadcast u64 loads
//    per lane (L2/L3-hot) instead of 64 scalar HBM loads.
//  - packed bits live in the dead k_lo region; QK proj no longer writes k_lo.
// Tiled layout: chunk(row,k) at (row>>4)*16*ld + (k>>3)*128 + (row&15)*8+(k&7)
//  -> gld16 staging lane l fetches base+l*16 (1KB contiguous), lands in
//     fragment order, ds_read base+lane*16, zero bank conflicts (R6-proven).

#define BB 8
#define SS 2048
#define TT 2048
#define EE 512

typedef __attribute__((ext_vector_type(8))) short short8;
typedef __attribute__((ext_vector_type(4))) float f32x4;

__device__ __forceinline__ uint16_t f2bf(float f) {      // RNE fp32->bf16
  uint32_t u = __builtin_bit_cast(uint32_t, f);
  u += 0x7fffu + ((u >> 16) & 1u);
  return (uint16_t)(u >> 16);
}
__device__ __forceinline__ float bf2f(uint16_t h) {
  uint32_t u = ((uint32_t)h) << 16;
  return __builtin_bit_cast(float, u);
}

// tiled element offset (ld = row length in elements, multiple of 8)
__device__ __forceinline__ size_t toff(int row, int col, int ld) {
  return (size_t)(row >> 4) * ((size_t)ld << 4) + ((size_t)(col >> 3) << 7)
       + ((row & 15) << 3) + (col & 7);
}

// async global->LDS, 16B per lane; LDS dest = wave-uniform base + lane*16
__device__ __forceinline__ void gld16(const void* g, void* l) {
  __builtin_amdgcn_global_load_lds(
      (const __attribute__((address_space(1))) void*)g,
      (__attribute__((address_space(3))) void*)l, 16, 0, 0);
}

// ---------------------------------------------------------------------------
// NT MFMA GEMM: C[m,n] = sum_k A[m,k]*B[n,k]  (both K-major, TILED layout)
// ASRC: 0 = bf16 hi+lo arrays   1 = bf16 hi only
// BSRC: 0 = bf16 hi+lo arrays   1 = bf16 hi only
//   terms: A0/B0 -> 3 (hh, hl, lh);  A0/B1 -> 2 (hh, lh);  A1/B1 -> 1
// EPI:  0 = +biasz[col], split bf16 out tiled (Cp=hi, C2=lo; lo only z==0)
//       1 = +bias[row], bf16 out tiled                        (vT proj)
//       4 = +resid, fp32 out ROW-MAJOR                        (Wo + residual)
//       5 = packed mask -> P_u=exp(L-60) bf16 tiled + atomicAdd row-sum -> sZ
//       6 = val / sZ[row], bf16 out tiled                     (PV normalize)
// WN: wave n-tiles (4 -> 128-wide block). M-tile = 128. 256 threads.
// ---------------------------------------------------------------------------
template<int ASRC, int BSRC, int EPI, int WN>
__global__ __launch_bounds__(256, 2) void mgemm(
    const void* __restrict__ Ap, const void* __restrict__ Alo,
    const void* __restrict__ Bp, const void* __restrict__ Blo,
    void* __restrict__ Cp, void* __restrict__ C2,
    const float* __restrict__ bias, const float* __restrict__ bias2,
    const float* __restrict__ resid,
    const int* __restrict__ mask, float* __restrict__ sZ,
    int K, int lda, int ldb, int ldc,
    size_t sA, size_t sB, size_t sC, size_t sM)
{
  constexpr bool ALOARR = (ASRC == 0);
  constexpr bool BLOARR = (BSRC == 0);
  constexpr bool T3     = (ASRC == 0) && (BSRC == 0);
  constexpr bool T2     = (ASRC == 0) && (BSRC == 1);
  constexpr int  BN     = 32 * WN;
  constexpr int  ABYTES = ALOARR ? 16384 : 8192;
  constexpr int  BBYTES = BLOARR ? BN * 128 : BN * 64;

  __shared__ char smem[ABYTES + BBYTES];

  const int tid  = threadIdx.x;
  const int lane = tid & 63, wv = tid >> 6;
  const int z    = blockIdx.z;
  const int bm   = blockIdx.y * 128;
  const int bn   = blockIdx.x * BN;
  const int fr   = lane & 15;            // fragment row/col
  const int wm   = (wv & 1) * 64;
  const int wn   = (wv >> 1) * (16 * WN);

  const f32x4 zero = {0.f, 0.f, 0.f, 0.f};
  f32x4 acc[4][WN];
#pragma unroll
  for (int i = 0; i < 4; ++i)
#pragma unroll
    for (int j = 0; j < WN; ++j) acc[i][j] = zero;

  // tiled layout: staging lane l's offset within a (16-row x 32-k) seg-tile
  // is just l*8 elements (l*16 bytes) -- fully contiguous per gld16.
  const size_t loff = (size_t)lane * 8;
  const uint16_t* gAh = (const uint16_t*)Ap + sA * z + (size_t)(bm >> 4) * 16 * lda + loff;
  const uint16_t* gAl = ALOARR ? (const uint16_t*)Alo + sA * z + (size_t)(bm >> 4) * 16 * lda + loff : nullptr;
  const uint16_t* gBh = (const uint16_t*)Bp + sB * z + (size_t)(bn >> 4) * 16 * ldb + loff;
  const uint16_t* gBl = BLOARR ? (const uint16_t*)Blo + sB * z + (size_t)(bn >> 4) * 16 * ldb + loff : nullptr;

  for (int k0 = 0; k0 < K; k0 += 32) {
    const size_t ka = (size_t)k0 * 16;           // (k0>>3)*128 elements
    __syncthreads();                       // previous tiles fully consumed
    // ---- stage A (8 segs x 1KB each) ----
#pragma unroll
    for (int t = 0; t < 2; ++t) { int s = wv + t * 4;
      gld16(gAh + (size_t)s * 16 * lda + ka, &smem[s * 1024]); }
    if constexpr (ALOARR) {
#pragma unroll
      for (int t = 0; t < 2; ++t) { int s = wv + t * 4;
        gld16(gAl + (size_t)s * 16 * lda + ka, &smem[8192 + s * 1024]); }
    }
    // ---- stage B ----
#pragma unroll
    for (int t = 0; t < WN / 2; ++t) { int s = wv + t * 4;
      gld16(gBh + (size_t)s * 16 * ldb + ka, &smem[ABYTES + s * 1024]); }
    if constexpr (BLOARR) {
#pragma unroll
      for (int t = 0; t < WN / 2; ++t) { int s = wv + t * 4;
        gld16(gBl + (size_t)s * 16 * ldb + ka, &smem[ABYTES + BN * 64 + s * 1024]); }
    }
    __syncthreads();                       // staging landed

    // ---- fragments: each wave reads base + lane*16 (conflict-free) ----
    short8 ah[4], bh[WN], al_[4], bl_[WN];
#pragma unroll
    for (int i = 0; i < 4; ++i) {
      const char* p = smem + ((wm >> 4) + i) * 1024 + (lane << 4);
      ah[i] = *(const short8*)p;
      if constexpr (ALOARR) al_[i] = *(const short8*)(p + 8192);
    }
#pragma unroll
    for (int j = 0; j < WN; ++j) {
      const char* p = smem + ABYTES + ((wn >> 4) + j) * 1024 + (lane << 4);
      bh[j] = *(const short8*)p;
      if constexpr (BLOARR) bl_[j] = *(const short8*)(p + BN * 64);
    }
    // ---- MFMA ----
#pragma unroll
    for (int i = 0; i < 4; ++i)
#pragma unroll
      for (int j = 0; j < WN; ++j) {
        acc[i][j] = __builtin_amdgcn_mfma_f32_16x16x32_bf16(ah[i], bh[j], acc[i][j], 0, 0, 0);
        if constexpr (T3) {
          acc[i][j] = __builtin_amdgcn_mfma_f32_16x16x32_bf16(ah[i], bl_[j], acc[i][j], 0, 0, 0);
          acc[i][j] = __builtin_amdgcn_mfma_f32_16x16x32_bf16(al_[i], bh[j], acc[i][j], 0, 0, 0);
        } else if constexpr (T2) {
          acc[i][j] = __builtin_amdgcn_mfma_f32_16x16x32_bf16(al_[i], bh[j], acc[i][j], 0, 0, 0);
        }
      }
  }

  // ---- epilogue: C/D layout col=lane&15, row=(lane>>4)*4+reg ----
  if constexpr (EPI == 5) {
    // mask is PACKED BITS: u64 word = 64 cols, bit c = col&63, 1 = masked.
    // Wave's n-span [bn+wn, bn+wn+64) is 64-aligned -> one word per row.
    const unsigned long long* __restrict__ mb = (const unsigned long long*)mask;
    const size_t mrow = (size_t)TT >> 6;           // words per row
    const size_t mbase = (size_t)z * SS * mrow + ((size_t)(bn + wn) >> 6);
    unsigned long long mw[4][4];
#pragma unroll
    for (int i = 0; i < 4; ++i)
#pragma unroll
      for (int g = 0; g < 4; ++g) {
        const int row = bm + wm + i * 16 + (lane >> 4) * 4 + g;
        mw[i][g] = mb[mbase + (size_t)row * mrow];
      }
#pragma unroll
    for (int i = 0; i < 4; ++i) {
      const int row0 = bm + wm + i * 16 + (lane >> 4) * 4;
#pragma unroll
      for (int g = 0; g < 4; ++g) {
        const int row = row0 + g;
        float rs = 0.f;
#pragma unroll
        for (int j = 0; j < WN; ++j) {
          const int col = bn + wn + j * 16 + fr;
          const bool msk = (mw[i][g] >> (j * 16 + fr)) & 1ull;
          const float e = msk ? 0.f : __expf(acc[i][j][g] - 60.0f);
          ((uint16_t*)Cp)[sC * z + toff(row, col, ldc)] = f2bf(e);
          rs += e;
        }
        rs += __shfl_xor(rs, 1);
        rs += __shfl_xor(rs, 2);
        rs += __shfl_xor(rs, 4);
        rs += __shfl_xor(rs, 8);
        if ((lane & 15) == 0) atomicAdd(&sZ[(size_t)z * SS + row], rs);
      }
    }
  } else {
#pragma unroll
    for (int i = 0; i < 4; ++i) {
      const int row0 = bm + wm + i * 16 + (lane >> 4) * 4;
#pragma unroll
      for (int g = 0; g < 4; ++g) {
        const int row = row0 + g;
        float invZ = 1.0f;
        if constexpr (EPI == 6) invZ = 1.0f / sZ[(size_t)z * SS + row];
#pragma unroll
        for (int j = 0; j < WN; ++j) {
          const int col = bn + wn + j * 16 + fr;
          float v = acc[i][j][g];
          if constexpr (EPI == 0) {
            const float* bp = (z == 0) ? bias : bias2;
            const size_t ci = sC * z + toff(row, col, ldc);
            v += bp[col];
            uint16_t h = f2bf(v);
            ((uint16_t*)Cp)[ci] = h;
            // lo term only consumed for q (z==0); k_lo region now holds
            // the packed mask bits -- must NOT be written.
            if (z == 0) ((uint16_t*)C2)[ci] = f2bf(v - bf2f(h));
          } else if constexpr (EPI == 1) {
            v += bias[row];
            ((uint16_t*)Cp)[sC * z + toff(row, col, ldc)] = f2bf(v);
          } else if constexpr (EPI == 4) {
            v += resid[(size_t)row * ldc + col];
            ((float*)Cp)[sC * z + (size_t)row * ldc + col] = v;
          } else {  // EPI == 6
            ((uint16_t*)Cp)[sC * z + toff(row, col, ldc)] = f2bf(v * invZ);
          }
        }
      }
    }
  }
}

// ---------------- fp32 [Rx512] row-major -> hi/lo bf16 TILED ---------------
// Core: one block = 16 rows x 128 cols = 2048 elements.
__device__ __forceinline__ void split_core(
    const float* __restrict__ x, uint16_t* __restrict__ hi,
    uint16_t* __restrict__ lo, int bid)
{
  __shared__ uint16_t lh[256 * 8 + 16 * 8];   // 16B chunks, 16B pad per 16
  __shared__ uint16_t ll[256 * 8 + 16 * 8];
  const int t   = threadIdx.x;
  const int seg = bid >> 2, q = bid & 3;

  const float* src = x + (size_t)(seg * 16 + (t >> 4)) * 512 + q * 128 + (t & 15) * 8;
  float4 a = *(const float4*)src;
  float4 b = *(const float4*)(src + 4);
  float v[8] = {a.x, a.y, a.z, a.w, b.x, b.y, b.z, b.w};

  const int slot = (t & 15) * 16 + (t >> 4);
  uint16_t* ph = lh + slot * 8 + (slot >> 4) * 8;
  uint16_t* pl = ll + slot * 8 + (slot >> 4) * 8;
#pragma unroll
  for (int e = 0; e < 8; ++e) {
    uint16_t h = f2bf(v[e]);
    ph[e] = h;
    pl[e] = f2bf(v[e] - bf2f(h));
  }
  __syncthreads();

  const uint16_t* qh = lh + t * 8 + (t >> 4) * 8;
  const uint16_t* ql = ll + t * 8 + (t >> 4) * 8;
  const size_t off = (size_t)seg * 8192 + (size_t)(q * 16 + (t >> 4)) * 128 + (t & 15) * 8;
  *(short8*)(hi + off) = *(const short8*)qh;
  *(short8*)(lo + off) = *(const short8*)ql;
}

// enc + emo splits + mask bit-pack in one launch: grid 8192 + 2048
__global__ __launch_bounds__(256) void split_pair(
    const float* __restrict__ x0, const float* __restrict__ x1,
    uint16_t* __restrict__ hi, uint16_t* __restrict__ lo, size_t stride,
    const int* __restrict__ mask, unsigned long long* __restrict__ mbits)
{
  if (blockIdx.x >= 8192) {
    // mask pack: wave reads 64 consecutive int32 (256B), ballot -> one u64
    const int lane = threadIdx.x & 63;
    const size_t wid = ((size_t)(blockIdx.x - 8192) * 256 + threadIdx.x) >> 6;
    const size_t nwords = (size_t)BB * SS * TT / 64;
    for (size_t w = wid; w < nwords; w += 2048 * 4) {
      const int m = mask[(w << 6) + lane];
      const unsigned long long b = __ballot(m != 0);
      if (lane == 0) mbits[w] = b;
    }
    return;
  }
  const int sel = blockIdx.x >> 12;            // 0: enc, 1: emo
  const int bid = blockIdx.x & 4095;
  split_core(sel ? x1 : x0, hi + sel * stride, lo + sel * stride, bid);
}

// 4 weight matrices in one launch: grid 512 (128 each); hi/lo bufs contiguous
__global__ __launch_bounds__(256) void split_w4(
    const float* __restrict__ x0, const float* __restrict__ x1,
    const float* __restrict__ x2, const float* __restrict__ x3,
    uint16_t* __restrict__ hi0, uint16_t* __restrict__ lo0, size_t stride)
{
  const int w   = blockIdx.x >> 7;
  const int bid = blockIdx.x & 127;
  const float* x = (w == 0) ? x0 : (w == 1) ? x1 : (w == 2) ? x2 : x3;
  split_core(x, hi0 + w * stride, lo0 + w * stride, bid);
}

// ---------------- fused LayerNorm epilogue (in-place safe) -----------------
__global__ __launch_bounds__(256) void ln_kernel(
    const float* __restrict__ X, const float* __restrict__ enc,
    const float* __restrict__ gamma, const float* __restrict__ beta,
    float* __restrict__ out)
{
  const int row = blockIdx.x * 4 + (threadIdx.x >> 6);
  const int lane = threadIdx.x & 63;
  const size_t base = (size_t)row * EE;
  const int o0 = lane * 4, o1 = 256 + lane * 4;

  float4 x0 = *(const float4*)(X + base + o0);
  float4 x1 = *(const float4*)(X + base + o1);
  float s = x0.x + x0.y + x0.z + x0.w + x1.x + x1.y + x1.z + x1.w;
#pragma unroll
  for (int off = 32; off > 0; off >>= 1) s += __shfl_xor(s, off);
  const float mean = s * (1.0f / 512.0f);

  float d[8] = {x0.x - mean, x0.y - mean, x0.z - mean, x0.w - mean,
                x1.x - mean, x1.y - mean, x1.z - mean, x1.w - mean};
  float s2 = 0.f;
#pragma unroll
  for (int i = 0; i < 8; ++i) s2 = fmaf(d[i], d[i], s2);
#pragma unroll
  for (int off = 32; off > 0; off >>= 1) s2 += __shfl_xor(s2, off);
  const float stdv = sqrtf(s2 * (1.0f / 512.0f));
  const float inv = 1.0f / (stdv + 1e-6f);

  float4 g0 = *(const float4*)(gamma + o0);
  float4 g1 = *(const float4*)(gamma + o1);
  float4 b0 = *(const float4*)(beta + o0);
  float4 b1 = *(const float4*)(beta + o1);
  float4 e0 = *(const float4*)(enc + base + o0);
  float4 e1 = *(const float4*)(enc + base + o1);

  float4 r0, r1;
  r0.x = e0.x + g0.x * d[0] * inv + b0.x;
  r0.y = e0.y + g0.y * d[1] * inv + b0.y;
  r0.z = e0.z + g0.z * d[2] * inv + b0.z;
  r0.w = e0.w + g0.w * d[3] * inv + b0.w;
  r1.x = e1.x + g1.x * d[4] * inv + b1.x;
  r1.y = e1.y + g1.y * d[5] * inv + b1.y;
  r1.z = e1.z + g1.z * d[6] * inv + b1.z;
  r1.w = e1.w + g1.w * d[7] * inv + b1.w;
  *(float4*)(out + base + o0) = r0;
  *(float4*)(out + base + o1) = r1;
}

extern "C" void kernel_launch(void* const* d_in, const int* in_sizes, int n_in,
                              void* d_out, int out_size, void* d_ws, size_t ws_size,
                              hipStream_t stream) {
  const float* enc   = (const float*)d_in[0];
  const float* emo   = (const float*)d_in[1];
  const int*   mask  = (const int*)d_in[2];
  const float* Wq    = (const float*)d_in[3];
  const float* bq    = (const float*)d_in[4];
  const float* Wk    = (const float*)d_in[5];
  const float* bk    = (const float*)d_in[6];
  const float* Wv    = (const float*)d_in[7];
  const float* bv    = (const float*)d_in[8];
  const float* Wo    = (const float*)d_in[9];
  const float* gamma = (const float*)d_in[10];
  const float* beta  = (const float*)d_in[11];
  float* out = (float*)d_out;
  char*  ws  = (char*)d_ws;

  const size_t SZ = (size_t)BB * SS * EE;   // 8,388,608
  size_t off = 0;
  // adjacency matters: (enc_h,enc_l,emo_h,emo_l) stride 2SZ for fused QK A;
  // (q_hi,q_lo,k_hi,k_lo) stride 2SZ for fused QK C;
  // (wq_h,wq_l,wk_h,wk_l,...) stride 2*EE*EE for fused QK B and split_w4.
  uint16_t* enc_h = (uint16_t*)(ws + off); off += SZ * 2;
  uint16_t* enc_l = (uint16_t*)(ws + off); off += SZ * 2;
  uint16_t* emo_h = (uint16_t*)(ws + off); off += SZ * 2;
  uint16_t* emo_l = (uint16_t*)(ws + off); off += SZ * 2;
  uint16_t* q_hi  = (uint16_t*)(ws + off); off += SZ * 2;
  uint16_t* q_lo  = (uint16_t*)(ws + off); off += SZ * 2;
  uint16_t* k_hi  = (uint16_t*)(ws + off); off += SZ * 2;
  uint16_t* k_lo  = (uint16_t*)(ws + off); off += SZ * 2;  // holds packed mask
  uint16_t* vT    = (uint16_t*)(ws + off); off += SZ * 2;   // [E][B*T] tiled
  uint16_t* ctx   = (uint16_t*)(ws + off); off += SZ * 2;   // [B*S][E] tiled
  uint16_t* wq_h  = (uint16_t*)(ws + off); off += EE * EE * 2;
  uint16_t* wq_l  = (uint16_t*)(ws + off); off += EE * EE * 2;
  uint16_t* wk_h  = (uint16_t*)(ws + off); off += EE * EE * 2;
  uint16_t* wk_l  = (uint16_t*)(ws + off); off += EE * EE * 2;
  uint16_t* wv_h  = (uint16_t*)(ws + off); off += EE * EE * 2;
  uint16_t* wv_l  = (uint16_t*)(ws + off); off += EE * EE * 2;
  uint16_t* wo_h  = (uint16_t*)(ws + off); off += EE * EE * 2;
  uint16_t* wo_l  = (uint16_t*)(ws + off); off += EE * EE * 2;
  uint16_t* P_u   = (uint16_t*)(ws + off); off += (size_t)BB * SS * TT * 2;  // 67MB
  float*    sZ    = (float*)(ws + off);    off += (size_t)BB * SS * 4;
  (void)wk_l; (void)wv_l; (void)wo_l;

  // packed mask bits live in the (otherwise dead) k_lo region: 4.2MB of 16.8MB
  unsigned long long* mbits = (unsigned long long*)k_lo;

  const dim3 blk(256);

  // splits -> tiled hi/lo + mask bit-pack (2 launches)
  split_w4<<<dim3(512), blk, 0, stream>>>(Wq, Wk, Wv, Wo, wq_h, wq_l,
                                          (size_t)2 * EE * EE);
  split_pair<<<dim3(8192 + 2048), blk, 0, stream>>>(enc, emo, enc_h, enc_l,
                                                    (size_t)2 * SZ, mask, mbits);
  hipMemsetAsync(sZ, 0, (size_t)BB * SS * 4, stream);

  // Q,K projections fused (z=0: enc@Wq+bq -> q; z=1: emo@Wk+bk -> k), 3-term
  // (lo output written only for z==0; k_lo region now holds mask bits)
  mgemm<0, 0, 0, 4><<<dim3(4, 128, 2), blk, 0, stream>>>(
      enc_h, enc_l, wq_h, wq_l, q_hi, q_lo, bq, bk, nullptr, nullptr, nullptr,
      EE, EE, EE, EE, 2 * SZ, (size_t)2 * EE * EE, 2 * SZ, 0);
  // vT[e][b*T+t] = Wv[e,:].emo[b*T+t,:] + bv[e]   (tiled, ldc = B*T)
  mgemm<1, 1, 1, 4><<<dim3(128, 4, 1), blk, 0, stream>>>(
      wv_h, nullptr, emo_h, nullptr, vT, nullptr, bv, nullptr, nullptr,
      nullptr, nullptr, EE, EE, EE, BB * TT, 0, 0, 0, 0);

  // logits 2-term -> masked exp(L-60) bf16 tiled + row sums, all 8 batches
  mgemm<0, 1, 5, 4><<<dim3(16, 16, 8), blk, 0, stream>>>(
      q_hi, q_lo, k_hi, nullptr, P_u, nullptr, nullptr, nullptr, nullptr,
      (const int*)mbits, sZ, EE, EE, EE, TT,
      (size_t)SS * EE, (size_t)TT * EE, (size_t)SS * TT, 0);

  // ctx = (P_u @ V) / Z, all 8 batches (vT batch-z k-offset = z*T*16 elems)
  mgemm<1, 1, 6, 4><<<dim3(4, 16, 8), blk, 0, stream>>>(
      P_u, nullptr, vT, nullptr, ctx, nullptr, nullptr, nullptr, nullptr,
      nullptr, sZ, TT, TT, BB * TT, EE,
      (size_t)SS * TT, (size_t)TT * 16, (size_t)SS * EE, 0);

  // x = enc + ctx @ Wo^T  (fp32 row-major into d_out)
  mgemm<1, 1, 4, 4><<<dim3(4, 128, 1), blk, 0, stream>>>(
      ctx, nullptr, wo_h, nullptr, out, nullptr, nullptr, nullptr, enc,
      nullptr, nullptr, EE, EE, EE, EE, 0, 0, 0, 0);
  // out = enc + LN(x), in place
  ln_kernel<<<dim3(BB * SS / 4), blk, 0, stream>>>(out, enc, gamma, beta, out);
}

// Round 2
// 541.037 us; speedup vs baseline: 1.0021x; 1.0021x over previous
//
#include <hip/hip_runtime.h>
#include <math.h>
#include <stdint.h>

// AttnEmo: B=8, S=T=2048, E=512. All-MFMA, fixed-shift unnormalized softmax.
// R9 (on R8):
//  - mask bit-pack vectorized: each lane builds its own u64 from 64 contiguous
//    ints via 16x int4 loads (256B/lane in flight) -- no ballot, no serial
//    32-iter loop. R8's 4B/lane + dependent-ballot version was latency-bound
//    (22% BW, 95us); this is a pure streaming pass.
// R8: mask bit-packed once (134MB int32 -> 4.2MB bits, lives in dead k_lo);
//     logits epilogue does 16 broadcast u64 loads/lane instead of 64 HBM loads.
// Tiled layout: chunk(row,k) at (row>>4)*16*ld + (k>>3)*128 + (row&15)*8+(k&7)
//  -> gld16 staging lane l fetches base+l*16 (1KB contiguous), lands in
//     fragment order, ds_read base+lane*16, zero bank conflicts (R6-proven).

#define BB 8
#define SS 2048
#define TT 2048
#define EE 512

typedef __attribute__((ext_vector_type(8))) short short8;
typedef __attribute__((ext_vector_type(4))) float f32x4;

__device__ __forceinline__ uint16_t f2bf(float f) {      // RNE fp32->bf16
  uint32_t u = __builtin_bit_cast(uint32_t, f);
  u += 0x7fffu + ((u >> 16) & 1u);
  return (uint16_t)(u >> 16);
}
__device__ __forceinline__ float bf2f(uint16_t h) {
  uint32_t u = ((uint32_t)h) << 16;
  return __builtin_bit_cast(float, u);
}

// tiled element offset (ld = row length in elements, multiple of 8)
__device__ __forceinline__ size_t toff(int row, int col, int ld) {
  return (size_t)(row >> 4) * ((size_t)ld << 4) + ((size_t)(col >> 3) << 7)
       + ((row & 15) << 3) + (col & 7);
}

// async global->LDS, 16B per lane; LDS dest = wave-uniform base + lane*16
__device__ __forceinline__ void gld16(const void* g, void* l) {
  __builtin_amdgcn_global_load_lds(
      (const __attribute__((address_space(1))) void*)g,
      (__attribute__((address_space(3))) void*)l, 16, 0, 0);
}

// ---------------------------------------------------------------------------
// NT MFMA GEMM: C[m,n] = sum_k A[m,k]*B[n,k]  (both K-major, TILED layout)
// ASRC: 0 = bf16 hi+lo arrays   1 = bf16 hi only
// BSRC: 0 = bf16 hi+lo arrays   1 = bf16 hi only
//   terms: A0/B0 -> 3 (hh, hl, lh);  A0/B1 -> 2 (hh, lh);  A1/B1 -> 1
// EPI:  0 = +biasz[col], split bf16 out tiled (Cp=hi, C2=lo; lo only z==0)
//       1 = +bias[row], bf16 out tiled                        (vT proj)
//       4 = +resid, fp32 out ROW-MAJOR                        (Wo + residual)
//       5 = packed mask -> P_u=exp(L-60) bf16 tiled + atomicAdd row-sum -> sZ
//       6 = val / sZ[row], bf16 out tiled                     (PV normalize)
// WN: wave n-tiles (4 -> 128-wide block). M-tile = 128. 256 threads.
// ---------------------------------------------------------------------------
template<int ASRC, int BSRC, int EPI, int WN>
__global__ __launch_bounds__(256, 2) void mgemm(
    const void* __restrict__ Ap, const void* __restrict__ Alo,
    const void* __restrict__ Bp, const void* __restrict__ Blo,
    void* __restrict__ Cp, void* __restrict__ C2,
    const float* __restrict__ bias, const float* __restrict__ bias2,
    const float* __restrict__ resid,
    const int* __restrict__ mask, float* __restrict__ sZ,
    int K, int lda, int ldb, int ldc,
    size_t sA, size_t sB, size_t sC, size_t sM)
{
  constexpr bool ALOARR = (ASRC == 0);
  constexpr bool BLOARR = (BSRC == 0);
  constexpr bool T3     = (ASRC == 0) && (BSRC == 0);
  constexpr bool T2     = (ASRC == 0) && (BSRC == 1);
  constexpr int  BN     = 32 * WN;
  constexpr int  ABYTES = ALOARR ? 16384 : 8192;
  constexpr int  BBYTES = BLOARR ? BN * 128 : BN * 64;

  __shared__ char smem[ABYTES + BBYTES];

  const int tid  = threadIdx.x;
  const int lane = tid & 63, wv = tid >> 6;
  const int z    = blockIdx.z;
  const int bm   = blockIdx.y * 128;
  const int bn   = blockIdx.x * BN;
  const int fr   = lane & 15;            // fragment row/col
  const int wm   = (wv & 1) * 64;
  const int wn   = (wv >> 1) * (16 * WN);

  const f32x4 zero = {0.f, 0.f, 0.f, 0.f};
  f32x4 acc[4][WN];
#pragma unroll
  for (int i = 0; i < 4; ++i)
#pragma unroll
    for (int j = 0; j < WN; ++j) acc[i][j] = zero;

  // tiled layout: staging lane l's offset within a (16-row x 32-k) seg-tile
  // is just l*8 elements (l*16 bytes) -- fully contiguous per gld16.
  const size_t loff = (size_t)lane * 8;
  const uint16_t* gAh = (const uint16_t*)Ap + sA * z + (size_t)(bm >> 4) * 16 * lda + loff;
  const uint16_t* gAl = ALOARR ? (const uint16_t*)Alo + sA * z + (size_t)(bm >> 4) * 16 * lda + loff : nullptr;
  const uint16_t* gBh = (const uint16_t*)Bp + sB * z + (size_t)(bn >> 4) * 16 * ldb + loff;
  const uint16_t* gBl = BLOARR ? (const uint16_t*)Blo + sB * z + (size_t)(bn >> 4) * 16 * ldb + loff : nullptr;

  for (int k0 = 0; k0 < K; k0 += 32) {
    const size_t ka = (size_t)k0 * 16;           // (k0>>3)*128 elements
    __syncthreads();                       // previous tiles fully consumed
    // ---- stage A (8 segs x 1KB each) ----
#pragma unroll
    for (int t = 0; t < 2; ++t) { int s = wv + t * 4;
      gld16(gAh + (size_t)s * 16 * lda + ka, &smem[s * 1024]); }
    if constexpr (ALOARR) {
#pragma unroll
      for (int t = 0; t < 2; ++t) { int s = wv + t * 4;
        gld16(gAl + (size_t)s * 16 * lda + ka, &smem[8192 + s * 1024]); }
    }
    // ---- stage B ----
#pragma unroll
    for (int t = 0; t < WN / 2; ++t) { int s = wv + t * 4;
      gld16(gBh + (size_t)s * 16 * ldb + ka, &smem[ABYTES + s * 1024]); }
    if constexpr (BLOARR) {
#pragma unroll
      for (int t = 0; t < WN / 2; ++t) { int s = wv + t * 4;
        gld16(gBl + (size_t)s * 16 * ldb + ka, &smem[ABYTES + BN * 64 + s * 1024]); }
    }
    __syncthreads();                       // staging landed

    // ---- fragments: each wave reads base + lane*16 (conflict-free) ----
    short8 ah[4], bh[WN], al_[4], bl_[WN];
#pragma unroll
    for (int i = 0; i < 4; ++i) {
      const char* p = smem + ((wm >> 4) + i) * 1024 + (lane << 4);
      ah[i] = *(const short8*)p;
      if constexpr (ALOARR) al_[i] = *(const short8*)(p + 8192);
    }
#pragma unroll
    for (int j = 0; j < WN; ++j) {
      const char* p = smem + ABYTES + ((wn >> 4) + j) * 1024 + (lane << 4);
      bh[j] = *(const short8*)p;
      if constexpr (BLOARR) bl_[j] = *(const short8*)(p + BN * 64);
    }
    // ---- MFMA ----
#pragma unroll
    for (int i = 0; i < 4; ++i)
#pragma unroll
      for (int j = 0; j < WN; ++j) {
        acc[i][j] = __builtin_amdgcn_mfma_f32_16x16x32_bf16(ah[i], bh[j], acc[i][j], 0, 0, 0);
        if constexpr (T3) {
          acc[i][j] = __builtin_amdgcn_mfma_f32_16x16x32_bf16(ah[i], bl_[j], acc[i][j], 0, 0, 0);
          acc[i][j] = __builtin_amdgcn_mfma_f32_16x16x32_bf16(al_[i], bh[j], acc[i][j], 0, 0, 0);
        } else if constexpr (T2) {
          acc[i][j] = __builtin_amdgcn_mfma_f32_16x16x32_bf16(al_[i], bh[j], acc[i][j], 0, 0, 0);
        }
      }
  }

  // ---- epilogue: C/D layout col=lane&15, row=(lane>>4)*4+reg ----
  if constexpr (EPI == 5) {
    // mask is PACKED BITS: u64 word = 64 cols, bit c = col&63, 1 = masked.
    // Wave's n-span [bn+wn, bn+wn+64) is 64-aligned -> one word per row.
    const unsigned long long* __restrict__ mb = (const unsigned long long*)mask;
    const size_t mrow = (size_t)TT >> 6;           // words per row
    const size_t mbase = (size_t)z * SS * mrow + ((size_t)(bn + wn) >> 6);
    unsigned long long mw[4][4];
#pragma unroll
    for (int i = 0; i < 4; ++i)
#pragma unroll
      for (int g = 0; g < 4; ++g) {
        const int row = bm + wm + i * 16 + (lane >> 4) * 4 + g;
        mw[i][g] = mb[mbase + (size_t)row * mrow];
      }
#pragma unroll
    for (int i = 0; i < 4; ++i) {
      const int row0 = bm + wm + i * 16 + (lane >> 4) * 4;
#pragma unroll
      for (int g = 0; g < 4; ++g) {
        const int row = row0 + g;
        float rs = 0.f;
#pragma unroll
        for (int j = 0; j < WN; ++j) {
          const int col = bn + wn + j * 16 + fr;
          const bool msk = (mw[i][g] >> (j * 16 + fr)) & 1ull;
          const float e = msk ? 0.f : __expf(acc[i][j][g] - 60.0f);
          ((uint16_t*)Cp)[sC * z + toff(row, col, ldc)] = f2bf(e);
          rs += e;
        }
        rs += __shfl_xor(rs, 1);
        rs += __shfl_xor(rs, 2);
        rs += __shfl_xor(rs, 4);
        rs += __shfl_xor(rs, 8);
        if ((lane & 15) == 0) atomicAdd(&sZ[(size_t)z * SS + row], rs);
      }
    }
  } else {
#pragma unroll
    for (int i = 0; i < 4; ++i) {
      const int row0 = bm + wm + i * 16 + (lane >> 4) * 4;
#pragma unroll
      for (int g = 0; g < 4; ++g) {
        const int row = row0 + g;
        float invZ = 1.0f;
        if constexpr (EPI == 6) invZ = 1.0f / sZ[(size_t)z * SS + row];
#pragma unroll
        for (int j = 0; j < WN; ++j) {
          const int col = bn + wn + j * 16 + fr;
          float v = acc[i][j][g];
          if constexpr (EPI == 0) {
            const float* bp = (z == 0) ? bias : bias2;
            const size_t ci = sC * z + toff(row, col, ldc);
            v += bp[col];
            uint16_t h = f2bf(v);
            ((uint16_t*)Cp)[ci] = h;
            // lo term only consumed for q (z==0); k_lo region now holds
            // the packed mask bits -- must NOT be written.
            if (z == 0) ((uint16_t*)C2)[ci] = f2bf(v - bf2f(h));
          } else if constexpr (EPI == 1) {
            v += bias[row];
            ((uint16_t*)Cp)[sC * z + toff(row, col, ldc)] = f2bf(v);
          } else if constexpr (EPI == 4) {
            v += resid[(size_t)row * ldc + col];
            ((float*)Cp)[sC * z + (size_t)row * ldc + col] = v;
          } else {  // EPI == 6
            ((uint16_t*)Cp)[sC * z + toff(row, col, ldc)] = f2bf(v * invZ);
          }
        }
      }
    }
  }
}

// ---------------- fp32 [Rx512] row-major -> hi/lo bf16 TILED ---------------
// Core: one block = 16 rows x 128 cols = 2048 elements.
__device__ __forceinline__ void split_core(
    const float* __restrict__ x, uint16_t* __restrict__ hi,
    uint16_t* __restrict__ lo, int bid)
{
  __shared__ uint16_t lh[256 * 8 + 16 * 8];   // 16B chunks, 16B pad per 16
  __shared__ uint16_t ll[256 * 8 + 16 * 8];
  const int t   = threadIdx.x;
  const int seg = bid >> 2, q = bid & 3;

  const float* src = x + (size_t)(seg * 16 + (t >> 4)) * 512 + q * 128 + (t & 15) * 8;
  float4 a = *(const float4*)src;
  float4 b = *(const float4*)(src + 4);
  float v[8] = {a.x, a.y, a.z, a.w, b.x, b.y, b.z, b.w};

  const int slot = (t & 15) * 16 + (t >> 4);
  uint16_t* ph = lh + slot * 8 + (slot >> 4) * 8;
  uint16_t* pl = ll + slot * 8 + (slot >> 4) * 8;
#pragma unroll
  for (int e = 0; e < 8; ++e) {
    uint16_t h = f2bf(v[e]);
    ph[e] = h;
    pl[e] = f2bf(v[e] - bf2f(h));
  }
  __syncthreads();

  const uint16_t* qh = lh + t * 8 + (t >> 4) * 8;
  const uint16_t* ql = ll + t * 8 + (t >> 4) * 8;
  const size_t off = (size_t)seg * 8192 + (size_t)(q * 16 + (t >> 4)) * 128 + (t & 15) * 8;
  *(short8*)(hi + off) = *(const short8*)qh;
  *(short8*)(lo + off) = *(const short8*)ql;
}

// enc + emo splits + mask bit-pack in one launch: grid 8192 + 2048
__global__ __launch_bounds__(256) void split_pair(
    const float* __restrict__ x0, const float* __restrict__ x1,
    uint16_t* __restrict__ hi, uint16_t* __restrict__ lo, size_t stride,
    const int* __restrict__ mask, unsigned long long* __restrict__ mbits)
{
  if (blockIdx.x >= 8192) {
    // mask pack: each lane builds its own u64 word from 64 contiguous ints
    // (16x int4 = 256B/lane in flight; no cross-lane ops, no serial loop).
    // words total = 8*2048*2048/64 = 524288; waves = 2048*4 = 8192;
    // 64 words per wave = exactly 1 word per lane.
    const int lane = threadIdx.x & 63;
    const size_t wvid = ((size_t)(blockIdx.x - 8192) * 256 + threadIdx.x) >> 6;
    const size_t w = wvid * 64 + lane;             // this lane's word index
    const int4* mp = (const int4*)mask + (w << 4); // 64 ints = 16 x int4
    unsigned long long bits = 0;
#pragma unroll
    for (int j = 0; j < 16; ++j) {
      const int4 m = mp[j];
      const unsigned nib = (unsigned)(m.x != 0) | ((unsigned)(m.y != 0) << 1)
                         | ((unsigned)(m.z != 0) << 2) | ((unsigned)(m.w != 0) << 3);
      bits |= (unsigned long long)nib << (j * 4);
    }
    mbits[w] = bits;
    return;
  }
  const int sel = blockIdx.x >> 12;            // 0: enc, 1: emo
  const int bid = blockIdx.x & 4095;
  split_core(sel ? x1 : x0, hi + sel * stride, lo + sel * stride, bid);
}

// 4 weight matrices in one launch: grid 512 (128 each); hi/lo bufs contiguous
__global__ __launch_bounds__(256) void split_w4(
    const float* __restrict__ x0, const float* __restrict__ x1,
    const float* __restrict__ x2, const float* __restrict__ x3,
    uint16_t* __restrict__ hi0, uint16_t* __restrict__ lo0, size_t stride)
{
  const int w   = blockIdx.x >> 7;
  const int bid = blockIdx.x & 127;
  const float* x = (w == 0) ? x0 : (w == 1) ? x1 : (w == 2) ? x2 : x3;
  split_core(x, hi0 + w * stride, lo0 + w * stride, bid);
}

// ---------------- fused LayerNorm epilogue (in-place safe) -----------------
__global__ __launch_bounds__(256) void ln_kernel(
    const float* __restrict__ X, const float* __restrict__ enc,
    const float* __restrict__ gamma, const float* __restrict__ beta,
    float* __restrict__ out)
{
  const int row = blockIdx.x * 4 + (threadIdx.x >> 6);
  const int lane = threadIdx.x & 63;
  const size_t base = (size_t)row * EE;
  const int o0 = lane * 4, o1 = 256 + lane * 4;

  float4 x0 = *(const float4*)(X + base + o0);
  float4 x1 = *(const float4*)(X + base + o1);
  float s = x0.x + x0.y + x0.z + x0.w + x1.x + x1.y + x1.z + x1.w;
#pragma unroll
  for (int off = 32; off > 0; off >>= 1) s += __shfl_xor(s, off);
  const float mean = s * (1.0f / 512.0f);

  float d[8] = {x0.x - mean, x0.y - mean, x0.z - mean, x0.w - mean,
                x1.x - mean, x1.y - mean, x1.z - mean, x1.w - mean};
  float s2 = 0.f;
#pragma unroll
  for (int i = 0; i < 8; ++i) s2 = fmaf(d[i], d[i], s2);
#pragma unroll
  for (int off = 32; off > 0; off >>= 1) s2 += __shfl_xor(s2, off);
  const float stdv = sqrtf(s2 * (1.0f / 512.0f));
  const float inv = 1.0f / (stdv + 1e-6f);

  float4 g0 = *(const float4*)(gamma + o0);
  float4 g1 = *(const float4*)(gamma + o1);
  float4 b0 = *(const float4*)(beta + o0);
  float4 b1 = *(const float4*)(beta + o1);
  float4 e0 = *(const float4*)(enc + base + o0);
  float4 e1 = *(const float4*)(enc + base + o1);

  float4 r0, r1;
  r0.x = e0.x + g0.x * d[0] * inv + b0.x;
  r0.y = e0.y + g0.y * d[1] * inv + b0.y;
  r0.z = e0.z + g0.z * d[2] * inv + b0.z;
  r0.w = e0.w + g0.w * d[3] * inv + b0.w;
  r1.x = e1.x + g1.x * d[4] * inv + b1.x;
  r1.y = e1.y + g1.y * d[5] * inv + b1.y;
  r1.z = e1.z + g1.z * d[6] * inv + b1.z;
  r1.w = e1.w + g1.w * d[7] * inv + b1.w;
  *(float4*)(out + base + o0) = r0;
  *(float4*)(out + base + o1) = r1;
}

extern "C" void kernel_launch(void* const* d_in, const int* in_sizes, int n_in,
                              void* d_out, int out_size, void* d_ws, size_t ws_size,
                              hipStream_t stream) {
  const float* enc   = (const float*)d_in[0];
  const float* emo   = (const float*)d_in[1];
  const int*   mask  = (const int*)d_in[2];
  const float* Wq    = (const float*)d_in[3];
  const float* bq    = (const float*)d_in[4];
  const float* Wk    = (const float*)d_in[5];
  const float* bk    = (const float*)d_in[6];
  const float* Wv    = (const float*)d_in[7];
  const float* bv    = (const float*)d_in[8];
  const float* Wo    = (const float*)d_in[9];
  const float* gamma = (const float*)d_in[10];
  const float* beta  = (const float*)d_in[11];
  float* out = (float*)d_out;
  char*  ws  = (char*)d_ws;

  const size_t SZ = (size_t)BB * SS * EE;   // 8,388,608
  size_t off = 0;
  // adjacency matters: (enc_h,enc_l,emo_h,emo_l) stride 2SZ for fused QK A;
  // (q_hi,q_lo,k_hi,k_lo) stride 2SZ for fused QK C;
  // (wq_h,wq_l,wk_h,wk_l,...) stride 2*EE*EE for fused QK B and split_w4.
  uint16_t* enc_h = (uint16_t*)(ws + off); off += SZ * 2;
  uint16_t* enc_l = (uint16_t*)(ws + off); off += SZ * 2;
  uint16_t* emo_h = (uint16_t*)(ws + off); off += SZ * 2;
  uint16_t* emo_l = (uint16_t*)(ws + off); off += SZ * 2;
  uint16_t* q_hi  = (uint16_t*)(ws + off); off += SZ * 2;
  uint16_t* q_lo  = (uint16_t*)(ws + off); off += SZ * 2;
  uint16_t* k_hi  = (uint16_t*)(ws + off); off += SZ * 2;
  uint16_t* k_lo  = (uint16_t*)(ws + off); off += SZ * 2;  // holds packed mask
  uint16_t* vT    = (uint16_t*)(ws + off); off += SZ * 2;   // [E][B*T] tiled
  uint16_t* ctx   = (uint16_t*)(ws + off); off += SZ * 2;   // [B*S][E] tiled
  uint16_t* wq_h  = (uint16_t*)(ws + off); off += EE * EE * 2;
  uint16_t* wq_l  = (uint16_t*)(ws + off); off += EE * EE * 2;
  uint16_t* wk_h  = (uint16_t*)(ws + off); off += EE * EE * 2;
  uint16_t* wk_l  = (uint16_t*)(ws + off); off += EE * EE * 2;
  uint16_t* wv_h  = (uint16_t*)(ws + off); off += EE * EE * 2;
  uint16_t* wv_l  = (uint16_t*)(ws + off); off += EE * EE * 2;
  uint16_t* wo_h  = (uint16_t*)(ws + off); off += EE * EE * 2;
  uint16_t* wo_l  = (uint16_t*)(ws + off); off += EE * EE * 2;
  uint16_t* P_u   = (uint16_t*)(ws + off); off += (size_t)BB * SS * TT * 2;  // 67MB
  float*    sZ    = (float*)(ws + off);    off += (size_t)BB * SS * 4;
  (void)wk_l; (void)wv_l; (void)wo_l;

  // packed mask bits live in the (otherwise dead) k_lo region: 4.2MB of 16.8MB
  unsigned long long* mbits = (unsigned long long*)k_lo;

  const dim3 blk(256);

  // splits -> tiled hi/lo + mask bit-pack (2 launches)
  split_w4<<<dim3(512), blk, 0, stream>>>(Wq, Wk, Wv, Wo, wq_h, wq_l,
                                          (size_t)2 * EE * EE);
  split_pair<<<dim3(8192 + 2048), blk, 0, stream>>>(enc, emo, enc_h, enc_l,
                                                    (size_t)2 * SZ, mask, mbits);
  hipMemsetAsync(sZ, 0, (size_t)BB * SS * 4, stream);

  // Q,K projections fused (z=0: enc@Wq+bq -> q; z=1: emo@Wk+bk -> k), 3-term
  // (lo output written only for z==0; k_lo region now holds mask bits)
  mgemm<0, 0, 0, 4><<<dim3(4, 128, 2), blk, 0, stream>>>(
      enc_h, enc_l, wq_h, wq_l, q_hi, q_lo, bq, bk, nullptr, nullptr, nullptr,
      EE, EE, EE, EE, 2 * SZ, (size_t)2 * EE * EE, 2 * SZ, 0);
  // vT[e][b*T+t] = Wv[e,:].emo[b*T+t,:] + bv[e]   (tiled, ldc = B*T)
  mgemm<1, 1, 1, 4><<<dim3(128, 4, 1), blk, 0, stream>>>(
      wv_h, nullptr, emo_h, nullptr, vT, nullptr, bv, nullptr, nullptr,
      nullptr, nullptr, EE, EE, EE, BB * TT, 0, 0, 0, 0);

  // logits 2-term -> masked exp(L-60) bf16 tiled + row sums, all 8 batches
  mgemm<0, 1, 5, 4><<<dim3(16, 16, 8), blk, 0, stream>>>(
      q_hi, q_lo, k_hi, nullptr, P_u, nullptr, nullptr, nullptr, nullptr,
      (const int*)mbits, sZ, EE, EE, EE, TT,
      (size_t)SS * EE, (size_t)TT * EE, (size_t)SS * TT, 0);

  // ctx = (P_u @ V) / Z, all 8 batches (vT batch-z k-offset = z*T*16 elems)
  mgemm<1, 1, 6, 4><<<dim3(4, 16, 8), blk, 0, stream>>>(
      P_u, nullptr, vT, nullptr, ctx, nullptr, nullptr, nullptr, nullptr,
      nullptr, sZ, TT, TT, BB * TT, EE,
      (size_t)SS * TT, (size_t)TT * 16, (size_t)SS * EE, 0);

  // x = enc + ctx @ Wo^T  (fp32 row-major into d_out)
  mgemm<1, 1, 4, 4><<<dim3(4, 128, 1), blk, 0, stream>>>(
      ctx, nullptr, wo_h, nullptr, out, nullptr, nullptr, nullptr, enc,
      nullptr, nullptr, EE, EE, EE, EE, 0, 0, 0, 0);
  // out = enc + LN(x), in place
  ln_kernel<<<dim3(BB * SS / 4), blk, 0, stream>>>(out, enc, gamma, beta, out);
}